// Round 2
// baseline (151.561 us; speedup 1.0000x reference)
//
#include <hip/hip_runtime.h>

// NeuralOoOScheduler: B=8192, W=64. Embedding path in the reference is dead
// (del emb) — live outputs: dep_matrix (B,64,64) f32 + readiness (B,64).
// Write-bound: ~136 MB out @ 6.3 TB/s floor ≈ 22 us kernel-side.
//
// R2 structure: one wave per batch, zero barriers, zero LDS.
//   lane = column j; rn/rm/rd live in lane registers.
//   row broadcast rd[i] via v_readlane (loop index uniform -> scalar).
//   readiness product accumulates per-lane; no reduction needed.

constexpr int Bv = 8192;
constexpr int Wv = 64;

__global__ __launch_bounds__(256) void ooo_kernel(
    const int* __restrict__ inst,
    const float* __restrict__ hw,
    float* __restrict__ dep,
    float* __restrict__ ready)
{
    const int b    = (blockIdx.x * blockDim.x + threadIdx.x) >> 6;  // batch = wave id
    const int lane = threadIdx.x & 63;                               // column j

    // score = h0*raw + h2*waw + h4 -> only 4 distinct sigmoid values
    const float h0 = hw[0], h2 = hw[2], h4 = hw[4];
    const float v00 = 1.f / (1.f + __expf(-(h4)));            // raw=0 waw=0
    const float v10 = 1.f / (1.f + __expf(-(h0 + h4)));       // raw=1 waw=0
    const float v01 = 1.f / (1.f + __expf(-(h2 + h4)));       // raw=0 waw=1
    const float v11 = 1.f / (1.f + __expf(-(h0 + h2 + h4)));  // raw=1 waw=1

    const int v   = inst[(size_t)b * Wv + lane];
    const int rn  = (v >> 5)  & 31;
    const int rm  = (v >> 16) & 31;
    const int rd  = v & 31;
    const int rdv = (rd < 31) ? rd : 64;   // waw sentinel: never matches rdi' below

    float prod = 1.f;
    float* const dep_col = dep + (size_t)b * Wv * Wv + lane;

#pragma unroll 8
    for (int i = 0; i < Wv; ++i) {
        int rdi = __builtin_amdgcn_readlane(rd, i);  // uniform i -> scalar broadcast
        rdi = (rdi < 31) ? rdi : 99;                  // invalid rd_i: matches nothing
        const bool raw = (rdi == rn) | (rdi == rm);
        const bool waw = (rdi == rdv);
        float d = waw ? (raw ? v11 : v01) : (raw ? v10 : v00);
        d = (lane > i) ? d : 0.f;                     // triu(k=1)
        __builtin_nontemporal_store(d, dep_col + i * Wv);
        prod *= (1.f - d);
    }
    ready[(size_t)b * Wv + lane] = prod;
}

extern "C" void kernel_launch(void* const* d_in, const int* in_sizes, int n_in,
                              void* d_out, int out_size, void* d_ws, size_t ws_size,
                              hipStream_t stream) {
    const int*   instructions   = (const int*)d_in[0];
    const float* hazard_weights = (const float*)d_in[5];

    float* dep   = (float*)d_out;                  // (B, W, W)
    float* ready = dep + (size_t)Bv * Wv * Wv;     // (B, W)

    // 8192 waves = one per batch; 2048 blocks x 256 thr -> whole grid co-resident
    ooo_kernel<<<(Bv * Wv) / 256, 256, 0, stream>>>(instructions, hazard_weights,
                                                    dep, ready);
}

// Round 3
// 148.231 us; speedup vs baseline: 1.0225x; 1.0225x over previous
//
#include <hip/hip_runtime.h>

// NeuralOoOScheduler: B=8192, W=64. Embedding path is dead (del emb).
// Live outputs: dep_matrix (B,64,64) f32 + readiness (B,64).
// Per timed iter the harness poison-fills 545 MB (~87 us, unavoidable);
// kernel floor is ~136 MB written. R3: wave-per-batch, zero barriers,
// float4 stores (1 KB/wave-inst), NO nontemporal flag so streaming stores
// allocate in the 256 MiB L3 and writeback drains off the critical path.

constexpr int Bv = 8192;
constexpr int Wv = 64;

__global__ __launch_bounds__(256) void ooo_kernel(
    const int* __restrict__ inst,
    const float* __restrict__ hw,
    float* __restrict__ dep,
    float* __restrict__ ready)
{
    const int b    = (blockIdx.x * blockDim.x + threadIdx.x) >> 6;  // batch = wave id
    const int lane = threadIdx.x & 63;

    // score = h0*raw + h2*waw + h4 -> only 4 distinct sigmoid values
    const float h0 = hw[0], h2 = hw[2], h4 = hw[4];
    const float v00 = 1.f / (1.f + __expf(-(h4)));
    const float v10 = 1.f / (1.f + __expf(-(h0 + h4)));
    const float v01 = 1.f / (1.f + __expf(-(h2 + h4)));
    const float v11 = 1.f / (1.f + __expf(-(h0 + h2 + h4)));

    // lane l initially holds instruction (= column AND row) index l
    const int v  = inst[(size_t)b * Wv + lane];
    const int rd = v & 31;

    // This lane's 4 owned columns: j = 4*(lane&15)+q
    const int j0 = (lane & 15) << 2;
    int  rnj[4], rmj[4], rdj[4];
    bool jv[4];
#pragma unroll
    for (int q = 0; q < 4; ++q) {
        const int vj = __shfl(v, j0 + q, 64);
        rnj[q] = (vj >> 5)  & 31;
        rmj[q] = (vj >> 16) & 31;
        rdj[q] = vj & 31;
        jv[q]  = rdj[q] < 31;
    }

    const int isub = lane >> 4;          // which of 4 rows within a store group
    float prod[4] = {1.f, 1.f, 1.f, 1.f};
    float* const out_base = dep + (size_t)b * Wv * Wv + isub * Wv + j0;

#pragma unroll
    for (int s = 0; s < 16; ++s) {
        const int  i   = (s << 2) + isub;      // row this lane covers this iter
        int rdi = __shfl(rd, i, 64);
        rdi = (rdi < 31) ? rdi : 99;           // invalid rd_i matches nothing
        float o[4];
#pragma unroll
        for (int q = 0; q < 4; ++q) {
            const bool raw = (rdi == rnj[q]) | (rdi == rmj[q]);
            const bool waw = jv[q] & (rdi == rdj[q]);
            float d = waw ? (raw ? v11 : v01) : (raw ? v10 : v00);
            d = ((j0 + q) > i) ? d : 0.f;      // triu(k=1)
            o[q] = d;
            prod[q] *= (1.f - d);
        }
        *(float4*)(out_base + (s << 2) * Wv) = make_float4(o[0], o[1], o[2], o[3]);
    }

    // readiness[j] = prod over all 64 rows; combine the 4 isub lane-groups
#pragma unroll
    for (int q = 0; q < 4; ++q) {
        prod[q] *= __shfl_xor(prod[q], 16, 64);
        prod[q] *= __shfl_xor(prod[q], 32, 64);
    }
    if (isub == 0) {  // lanes 0..15 hold the final product for their 4 columns
        *(float4*)(ready + (size_t)b * Wv + j0) =
            make_float4(prod[0], prod[1], prod[2], prod[3]);
    }
}

extern "C" void kernel_launch(void* const* d_in, const int* in_sizes, int n_in,
                              void* d_out, int out_size, void* d_ws, size_t ws_size,
                              hipStream_t stream) {
    const int*   instructions   = (const int*)d_in[0];
    const float* hazard_weights = (const float*)d_in[5];

    float* dep   = (float*)d_out;                  // (B, W, W)
    float* ready = dep + (size_t)Bv * Wv * Wv;     // (B, W)

    ooo_kernel<<<(Bv * Wv) / 256, 256, 0, stream>>>(instructions, hazard_weights,
                                                    dep, ready);
}